// Round 1
// baseline (1155.599 us; speedup 1.0000x reference)
//
#include <hip/hip_runtime.h>
#include <math.h>

// Shapes (fixed by reference setup_inputs)
constexpr int NB  = 2048;   // batch (graphs)
constexpr int NN  = 60;     // nodes per graph
constexpr int DD  = 6;      // max degree slots
constexpr int AF  = 37;     // atom features
constexpr int BFD = 6;      // bond features
constexpr int HH  = 128;    // hidden
constexpr int CC  = 12;     // classes
constexpr int IN1 = AF + BFD;   // 43
constexpr int IN2 = HH + BFD;   // 134
constexpr int T   = 512;        // threads per block

__global__ __launch_bounds__(T) void ngfp_kernel(
    const float* __restrict__ atoms,  // (B,N,AF)
    const float* __restrict__ bonds,  // (B,N,D,BFD)
    const int*   __restrict__ edges,  // (B,N,D), -1 pad
    const float* __restrict__ W1,     // (D,IN1,H)
    const float* __restrict__ b1,     // (D,H)
    const float* __restrict__ W2,     // (D,IN2,H)
    const float* __restrict__ b2,     // (D,H)
    const float* __restrict__ Wo,     // (IN2,H)
    const float* __restrict__ bo,     // (H)
    const float* __restrict__ Wfc,    // (H,C)
    const float* __restrict__ bfc,    // (C)
    float* __restrict__ out)          // (B,C)
{
    // LDS buffers. Phase-ping-pong:
    //  sA   : atoms (stride AF)  -> X1 (stride H) -> x4 (stride H)
    //  sFeat: feat1 (stride IN1) -> feat2 (stride IN2)
    //  sX   : X2 (pool1 out)     -> x3 (gcn2 out)
    __shared__ float sA[NN * HH];       // 30720 B
    __shared__ float sFeat[NN * IN2];   // 32160 B
    __shared__ float sX[NN * HH];       // 30720 B
    __shared__ float sBsum[NN * BFD];   // bonds.sum(2)
    __shared__ int   sEdges[NN * DD];
    __shared__ int   sDeg[NN];
    __shared__ float sPart[4 * HH];     // gout partial sums

    const int b = blockIdx.x;
    const int t = threadIdx.x;

    // ---- Phase 0: stage edges, atoms, bond-sums; compute degree ----
    for (int i = t; i < NN * DD; i += T) sEdges[i] = edges[b * NN * DD + i];
    for (int i = t; i < NN * AF; i += T) sA[i] = atoms[b * NN * AF + i];
    for (int i = t; i < NN * BFD; i += T) {
        int n = i / BFD, f = i - n * BFD;
        const float* bp = bonds + ((size_t)(b * NN + n) * DD) * BFD + f;
        float s = 0.f;
        #pragma unroll
        for (int d = 0; d < DD; ++d) s += bp[d * BFD];
        sBsum[i] = s;
    }
    __syncthreads();
    if (t < NN) {
        int dg = 0;
        #pragma unroll
        for (int d = 0; d < DD; ++d) dg += (sEdges[t * DD + d] != -1) ? 1 : 0;
        sDeg[t] = dg;
    }
    __syncthreads();

    // ---- Phase 1a: feat1[n][i] = (self+neighbors atoms | bsum), stride IN1 ----
    for (int idx = t; idx < NN * IN1; idx += T) {
        int n = idx / IN1, i = idx - n * IN1;
        float v;
        if (i < AF) {
            v = sA[n * AF + i];
            #pragma unroll
            for (int d = 0; d < DD; ++d) {
                int e = sEdges[n * DD + d];
                if (e >= 0) v += sA[e * AF + i];
            }
        } else {
            v = sBsum[n * BFD + (i - AF)];
        }
        sFeat[idx] = v;
    }
    __syncthreads();

    // ---- Phase 1b: X1[n][h] = relu(feat1[n] @ W1[deg[n]] + b1[deg[n]]) ----
    {
        const int h = t & (HH - 1);
        const int ng = t >> 7;            // 0..3
        for (int n = ng; n < NN; n += 4) {
            const int dg = sDeg[n];
            const float* Wr = W1 + (size_t)dg * IN1 * HH;
            const float* fr = sFeat + n * IN1;
            float acc = b1[dg * HH + h];
            #pragma unroll 43
            for (int i = 0; i < IN1; ++i) acc = fmaf(fr[i], Wr[i * HH + h], acc);
            sA[n * HH + h] = fmaxf(acc, 0.f);   // overwrite atoms buffer
        }
    }
    __syncthreads();

    // ---- Phase 2: pool1: X2 = max(self, neighbors) * (deg>0) ----
    for (int idx = t; idx < NN * HH; idx += T) {
        int n = idx >> 7, h = idx & (HH - 1);
        float m;
        if (sDeg[n] == 0) {
            m = 0.f;
        } else {
            m = sA[n * HH + h];
            #pragma unroll
            for (int d = 0; d < DD; ++d) {
                int e = sEdges[n * DD + d];
                if (e >= 0) m = fmaxf(m, sA[e * HH + h]);
            }
        }
        sX[idx] = m;
    }
    __syncthreads();

    // ---- Phase 3a: feat2[n][i] = (self+neighbors X2 | bsum), stride IN2 ----
    for (int idx = t; idx < NN * IN2; idx += T) {
        int n = idx / IN2, i = idx - n * IN2;
        float v;
        if (i < HH) {
            v = sX[n * HH + i];
            #pragma unroll
            for (int d = 0; d < DD; ++d) {
                int e = sEdges[n * DD + d];
                if (e >= 0) v += sX[e * HH + i];
            }
        } else {
            v = sBsum[n * BFD + (i - HH)];
        }
        sFeat[idx] = v;
    }
    __syncthreads();

    // ---- Phase 3b: x3[n][h] = relu(feat2[n] @ W2[deg[n]] + b2[deg[n]]) ----
    {
        const int h = t & (HH - 1);
        const int ng = t >> 7;
        for (int n = ng; n < NN; n += 4) {
            const int dg = sDeg[n];
            const float* Wr = W2 + (size_t)dg * IN2 * HH;
            const float* fr = sFeat + n * IN2;
            float acc = b2[dg * HH + h];
            #pragma unroll 8
            for (int i = 0; i < IN2; ++i) acc = fmaf(fr[i], Wr[i * HH + h], acc);
            sX[n * HH + h] = fmaxf(acc, 0.f);   // overwrite X2 (feat2 already built)
        }
    }
    __syncthreads();

    // ---- Phase 4: pool2: x4 = max(self, neighbors x3) * (deg>0) -> sA ----
    for (int idx = t; idx < NN * HH; idx += T) {
        int n = idx >> 7, h = idx & (HH - 1);
        float m;
        if (sDeg[n] == 0) {
            m = 0.f;
        } else {
            m = sX[n * HH + h];
            #pragma unroll
            for (int d = 0; d < DD; ++d) {
                int e = sEdges[n * DD + d];
                if (e >= 0) m = fmaxf(m, sX[e * HH + h]);
            }
        }
        sA[idx] = m;
    }
    __syncthreads();

    // ---- Phase 5: gout partials: per h, sum over node subset of tanh(feat@Wo+bo) ----
    {
        const int h = t & (HH - 1);
        const int ng = t >> 7;
        float sum = 0.f;
        for (int n = ng; n < NN; n += 4) {
            if (sDeg[n] > 0) {
                const float* fr = sA + n * HH;
                float acc = bo[h];
                #pragma unroll 8
                for (int i = 0; i < HH; ++i) acc = fmaf(fr[i], Wo[i * HH + h], acc);
                #pragma unroll
                for (int j = 0; j < BFD; ++j)
                    acc = fmaf(sBsum[n * BFD + j], Wo[(HH + j) * HH + h], acc);
                sum += tanhf(acc);
            }
        }
        sPart[ng * HH + h] = sum;
    }
    __syncthreads();

    // ---- Phase 6: reduce partials, final FC + sigmoid ----
    if (t < HH) {
        sPart[t] = sPart[t] + sPart[HH + t] + sPart[2 * HH + t] + sPart[3 * HH + t];
    }
    __syncthreads();
    if (t < CC) {
        float acc = bfc[t];
        #pragma unroll 16
        for (int i = 0; i < HH; ++i) acc = fmaf(sPart[i], Wfc[i * CC + t], acc);
        out[b * CC + t] = 1.f / (1.f + expf(-acc));
    }
}

extern "C" void kernel_launch(void* const* d_in, const int* in_sizes, int n_in,
                              void* d_out, int out_size, void* d_ws, size_t ws_size,
                              hipStream_t stream) {
    const float* atoms = (const float*)d_in[0];
    const float* bonds = (const float*)d_in[1];
    const int*   edges = (const int*)d_in[2];
    const float* W1  = (const float*)d_in[3];
    const float* b1  = (const float*)d_in[4];
    const float* W2  = (const float*)d_in[5];
    const float* b2  = (const float*)d_in[6];
    const float* Wo  = (const float*)d_in[7];
    const float* bo  = (const float*)d_in[8];
    const float* Wfc = (const float*)d_in[9];
    const float* bfc = (const float*)d_in[10];
    float* out = (float*)d_out;

    ngfp_kernel<<<NB, T, 0, stream>>>(atoms, bonds, edges, W1, b1, W2, b2,
                                      Wo, bo, Wfc, bfc, out);
}

// Round 2
// 838.138 us; speedup vs baseline: 1.3788x; 1.3788x over previous
//
#include <hip/hip_runtime.h>
#include <math.h>

// Shapes (fixed by reference setup_inputs)
constexpr int NB  = 2048;   // batch (graphs)
constexpr int NN  = 60;     // nodes per graph
constexpr int DD  = 6;      // max degree slots
constexpr int AF  = 37;     // atom features
constexpr int BFD = 6;      // bond features
constexpr int HH  = 128;    // hidden
constexpr int CC  = 12;     // classes
constexpr int IN1 = AF + BFD;   // 43
constexpr int IN2 = HH + BFD;   // 134
constexpr int IN1P = 44;        // padded stride (16B-aligned rows: 44*4=176=11*16)
constexpr int IN2P = 136;       // 136*4=544=34*16
constexpr int T   = 512;        // threads per block (8 waves)
constexpr int MAXT = 16;        // degree-pure tiles of 8: sum ceil(cnt_d/8) <= 14

// Degree-pure conv: each lane computes 8 nodes x 2 h-cols. One weight stream
// per tile (reused 16x in registers) -> 16 FMA per 4B/lane of L2 traffic.
template<int IN, int INP>
__device__ __forceinline__ void conv_tiles(
    const float* __restrict__ W,     // (D,IN,H) global
    const float* __restrict__ bias,  // (D,H) global
    const float* sFeat,              // LDS, stride INP, 16B-aligned rows
    float* sOut,                     // LDS, stride HH
    const int* sTileNode, const int* sTileDeg, int nT,
    int wv, int lane)
{
    const int h0 = lane, h1 = lane + 64;
    for (int tile = wv; tile < nT; tile += 8) {
        const int dg = sTileDeg[tile];
        int nd[8], nr[8];
        #pragma unroll
        for (int j = 0; j < 8; ++j) nd[j] = sTileNode[tile * 8 + j];
        const int n0 = nd[0];
        #pragma unroll
        for (int j = 0; j < 8; ++j) nr[j] = (nd[j] >= 0) ? nd[j] : n0;
        const float* Wr = W + (size_t)dg * IN * HH;
        const float bb0 = bias[dg * HH + h0];
        const float bb1 = bias[dg * HH + h1];
        float a0[8], a1[8];
        #pragma unroll
        for (int j = 0; j < 8; ++j) { a0[j] = bb0; a1[j] = bb1; }
        const float* fr[8];
        #pragma unroll
        for (int j = 0; j < 8; ++j) fr[j] = sFeat + nr[j] * INP;

        constexpr int KM = IN & ~3;
        for (int ic = 0; ic < KM; ic += 4) {
            float4 f[8];
            #pragma unroll
            for (int j = 0; j < 8; ++j) f[j] = *(const float4*)(fr[j] + ic);
            float w0[4], w1[4];
            #pragma unroll
            for (int k = 0; k < 4; ++k) {
                w0[k] = Wr[(ic + k) * HH + h0];
                w1[k] = Wr[(ic + k) * HH + h1];
            }
            #pragma unroll
            for (int j = 0; j < 8; ++j) {
                a0[j] = fmaf(f[j].x, w0[0], a0[j]);
                a0[j] = fmaf(f[j].y, w0[1], a0[j]);
                a0[j] = fmaf(f[j].z, w0[2], a0[j]);
                a0[j] = fmaf(f[j].w, w0[3], a0[j]);
                a1[j] = fmaf(f[j].x, w1[0], a1[j]);
                a1[j] = fmaf(f[j].y, w1[1], a1[j]);
                a1[j] = fmaf(f[j].z, w1[2], a1[j]);
                a1[j] = fmaf(f[j].w, w1[3], a1[j]);
            }
        }
        for (int i = KM; i < IN; ++i) {   // remainder (3 for IN1, 2 for IN2)
            const float w0v = Wr[i * HH + h0];
            const float w1v = Wr[i * HH + h1];
            #pragma unroll
            for (int j = 0; j < 8; ++j) {
                const float fv = fr[j][i];
                a0[j] = fmaf(fv, w0v, a0[j]);
                a1[j] = fmaf(fv, w1v, a1[j]);
            }
        }
        #pragma unroll
        for (int j = 0; j < 8; ++j) {
            if (nd[j] >= 0) {   // wave-uniform guard (skip duplicate pads)
                sOut[nd[j] * HH + h0] = fmaxf(a0[j], 0.f);
                sOut[nd[j] * HH + h1] = fmaxf(a1[j], 0.f);
            }
        }
    }
}

__global__ __launch_bounds__(T) void ngfp_kernel(
    const float* __restrict__ atoms,  // (B,N,AF)
    const float* __restrict__ bonds,  // (B,N,D,BFD)
    const int*   __restrict__ edges,  // (B,N,D), -1 pad
    const float* __restrict__ W1,     // (D,IN1,H)
    const float* __restrict__ b1,     // (D,H)
    const float* __restrict__ W2,     // (D,IN2,H)
    const float* __restrict__ b2,     // (D,H)
    const float* __restrict__ Wo,     // (IN2,H)
    const float* __restrict__ bo,     // (H)
    const float* __restrict__ Wfc,    // (H,C)
    const float* __restrict__ bfc,    // (C)
    float* __restrict__ out)          // (B,C)
{
    // sA: atoms (stride AF) -> X1 (stride H) -> x4 (stride H)
    // sU: {sFeat (stride 44/136) | sX = X2/x3 (stride H)}  -> later Wo (134x128)
    __shared__ float sA[NN * HH];          // 30720 B
    __shared__ float sU[IN2 * HH];         // 68608 B (union region)
    __shared__ float sBsum[NN * BFD];
    __shared__ int   sEdges[NN * DD];
    __shared__ int   sDeg[NN];
    __shared__ int   sCnt[8];
    __shared__ int   sTStart[8];
    __shared__ int   sTileNode[MAXT * 8];
    __shared__ int   sTileDeg[MAXT];
    __shared__ int   sNumTiles;
    __shared__ float sPart[8 * HH];        // 4096 B

    float* const sFeat = sU;               // rows 16B-aligned
    float* const sX    = sU + NN * IN2P;   // 8160 floats in; 8160+7680 <= 17152
    float* const sWo   = sU;               // alias, used after conv phases

    const int b = blockIdx.x;
    const int t = threadIdx.x;
    const int wv = t >> 6;
    const int lane = t & 63;
    const int h0 = lane, h1 = lane + 64;

    // ---- Phase 0: stage edges, atoms, bond-sums ----
    for (int i = t; i < NN * DD; i += T) sEdges[i] = edges[b * NN * DD + i];
    for (int i = t; i < NN * AF; i += T) sA[i] = atoms[b * NN * AF + i];
    for (int i = t; i < NN * BFD; i += T) {
        int n = i / BFD, f = i - n * BFD;
        const float* bp = bonds + ((size_t)(b * NN + n) * DD) * BFD + f;
        float s = 0.f;
        #pragma unroll
        for (int d = 0; d < DD; ++d) s += bp[d * BFD];
        sBsum[i] = s;
    }
    __syncthreads();

    // ---- Phase 0b: degree + feat1 build (feat1 needs no deg) ----
    if (t < NN) {
        int dg = 0;
        #pragma unroll
        for (int d = 0; d < DD; ++d) dg += (sEdges[t * DD + d] != -1) ? 1 : 0;
        sDeg[t] = dg;
    }
    // feat1[n][i] = (self+neighbor atoms | bsum), stride IN1P
    for (int idx = t; idx < NN * IN1; idx += T) {
        int n = idx / IN1, i = idx - n * IN1;
        float v;
        if (i < AF) {
            v = sA[n * AF + i];
            #pragma unroll
            for (int d = 0; d < DD; ++d) {
                int e = sEdges[n * DD + d];
                if (e >= 0) v += sA[e * AF + i];
            }
        } else {
            v = sBsum[n * BFD + (i - AF)];
        }
        sFeat[n * IN1P + i] = v;
    }
    __syncthreads();

    // ---- Phase 0c: degree-pure tiles of 8 (counting sort, pad -1) ----
    if (t < 7) {
        int c = 0;
        for (int n = 0; n < NN; ++n) c += (sDeg[n] == t) ? 1 : 0;
        sCnt[t] = c;
    }
    __syncthreads();
    if (t == 0) {
        int nt = 0;
        for (int d = 0; d < 7; ++d) { sTStart[d] = nt; nt += (sCnt[d] + 7) / 8; }
        sNumTiles = nt;
    }
    __syncthreads();
    if (t < 7) {
        const int d = t;
        int tile = sTStart[d], c = 0;
        for (int n = 0; n < NN; ++n) {
            if (sDeg[n] == d) {
                sTileNode[tile * 8 + (c & 7)] = n;
                ++c;
                if ((c & 7) == 0) ++tile;
            }
        }
        if ((c & 7) != 0) {
            for (int j = (c & 7); j < 8; ++j) sTileNode[tile * 8 + j] = -1;
        }
        const int tend = sTStart[d] + (sCnt[d] + 7) / 8;
        for (int tt = sTStart[d]; tt < tend; ++tt) sTileDeg[tt] = d;
    }
    __syncthreads();
    const int nT = sNumTiles;

    // ---- Phase 1: conv1: X1 = relu(feat1 @ W1[deg] + b1[deg]) -> sA ----
    conv_tiles<IN1, IN1P>(W1, b1, sFeat, sA, sTileNode, sTileDeg, nT, wv, lane);
    __syncthreads();

    // ---- Phase 2: pool1: X2 = max(self,nbrs)(X1) * (deg>0) -> sX ----
    for (int idx = t; idx < NN * (HH / 4); idx += T) {
        int n = idx >> 5, k = idx & 31;
        float4 m;
        if (sDeg[n] == 0) {
            m = make_float4(0.f, 0.f, 0.f, 0.f);
        } else {
            m = *(const float4*)(sA + n * HH + 4 * k);
            #pragma unroll
            for (int d = 0; d < DD; ++d) {
                int e = sEdges[n * DD + d];
                if (e >= 0) {
                    float4 v = *(const float4*)(sA + e * HH + 4 * k);
                    m.x = fmaxf(m.x, v.x); m.y = fmaxf(m.y, v.y);
                    m.z = fmaxf(m.z, v.z); m.w = fmaxf(m.w, v.w);
                }
            }
        }
        *(float4*)(sX + n * HH + 4 * k) = m;
    }
    __syncthreads();

    // ---- Phase 3a: feat2 = (self+nbr sums of X2 | bsum), stride IN2P ----
    for (int idx = t; idx < NN * (HH / 4); idx += T) {
        int n = idx >> 5, k = idx & 31;
        float4 v = *(const float4*)(sX + n * HH + 4 * k);
        #pragma unroll
        for (int d = 0; d < DD; ++d) {
            int e = sEdges[n * DD + d];
            if (e >= 0) {
                float4 u = *(const float4*)(sX + e * HH + 4 * k);
                v.x += u.x; v.y += u.y; v.z += u.z; v.w += u.w;
            }
        }
        *(float4*)(sFeat + n * IN2P + 4 * k) = v;
    }
    for (int idx = t; idx < NN * BFD; idx += T) {
        int n = idx / BFD, jb = idx - n * BFD;
        sFeat[n * IN2P + HH + jb] = sBsum[idx];
    }
    __syncthreads();

    // ---- Phase 3b: conv2: x3 = relu(feat2 @ W2[deg] + b2[deg]) -> sX ----
    conv_tiles<IN2, IN2P>(W2, b2, sFeat, sX, sTileNode, sTileDeg, nT, wv, lane);
    __syncthreads();

    // ---- Phase 4: pool2: x4 = max(self,nbrs)(x3) * (deg>0) -> sA ----
    for (int idx = t; idx < NN * (HH / 4); idx += T) {
        int n = idx >> 5, k = idx & 31;
        float4 m;
        if (sDeg[n] == 0) {
            m = make_float4(0.f, 0.f, 0.f, 0.f);
        } else {
            m = *(const float4*)(sX + n * HH + 4 * k);
            #pragma unroll
            for (int d = 0; d < DD; ++d) {
                int e = sEdges[n * DD + d];
                if (e >= 0) {
                    float4 v = *(const float4*)(sX + e * HH + 4 * k);
                    m.x = fmaxf(m.x, v.x); m.y = fmaxf(m.y, v.y);
                    m.z = fmaxf(m.z, v.z); m.w = fmaxf(m.w, v.w);
                }
            }
        }
        *(float4*)(sA + n * HH + 4 * k) = m;
    }
    __syncthreads();   // sFeat/sX now dead -> sU becomes sWo

    // ---- Phase 4b: stage Wo (134x128 = 68.6 KB) into LDS once per block ----
    for (int idx = t; idx < IN2 * HH; idx += T) sWo[idx] = Wo[idx];
    __syncthreads();

    // ---- Phase 5: gout: per-wave tile of 8 nodes; partial sums of tanh ----
    {
        const int base = wv * 8;
        int nd[8], nr[8];
        #pragma unroll
        for (int j = 0; j < 8; ++j) {
            int n = base + j;
            bool ok = (n < NN) && (sDeg[n] > 0);
            nd[j] = ok ? n : -1;
            nr[j] = (n < NN) ? n : 0;
        }
        const float bb0 = bo[h0], bb1 = bo[h1];
        float a0[8], a1[8];
        #pragma unroll
        for (int j = 0; j < 8; ++j) { a0[j] = bb0; a1[j] = bb1; }
        for (int ic = 0; ic < HH; ic += 4) {
            float4 f[8];
            #pragma unroll
            for (int j = 0; j < 8; ++j) f[j] = *(const float4*)(sA + nr[j] * HH + ic);
            float w0[4], w1[4];
            #pragma unroll
            for (int k = 0; k < 4; ++k) {
                w0[k] = sWo[(ic + k) * HH + h0];
                w1[k] = sWo[(ic + k) * HH + h1];
            }
            #pragma unroll
            for (int j = 0; j < 8; ++j) {
                a0[j] = fmaf(f[j].x, w0[0], a0[j]);
                a0[j] = fmaf(f[j].y, w0[1], a0[j]);
                a0[j] = fmaf(f[j].z, w0[2], a0[j]);
                a0[j] = fmaf(f[j].w, w0[3], a0[j]);
                a1[j] = fmaf(f[j].x, w1[0], a1[j]);
                a1[j] = fmaf(f[j].y, w1[1], a1[j]);
                a1[j] = fmaf(f[j].z, w1[2], a1[j]);
                a1[j] = fmaf(f[j].w, w1[3], a1[j]);
            }
        }
        #pragma unroll
        for (int jb = 0; jb < BFD; ++jb) {
            const float w0v = sWo[(HH + jb) * HH + h0];
            const float w1v = sWo[(HH + jb) * HH + h1];
            #pragma unroll
            for (int j = 0; j < 8; ++j) {
                const float fv = sBsum[nr[j] * BFD + jb];
                a0[j] = fmaf(fv, w0v, a0[j]);
                a1[j] = fmaf(fv, w1v, a1[j]);
            }
        }
        float p0 = 0.f, p1 = 0.f;
        #pragma unroll
        for (int j = 0; j < 8; ++j) {
            if (nd[j] >= 0) { p0 += tanhf(a0[j]); p1 += tanhf(a1[j]); }
        }
        sPart[wv * HH + h0] = p0;
        sPart[wv * HH + h1] = p1;
    }
    __syncthreads();

    // ---- Phase 6: reduce 8 wave-partials, final FC + sigmoid ----
    if (t < HH) {
        float s = 0.f;
        #pragma unroll
        for (int w = 0; w < 8; ++w) s += sPart[w * HH + t];
        sPart[t] = s;
    }
    __syncthreads();
    if (t < CC) {
        float acc = bfc[t];
        #pragma unroll 16
        for (int i = 0; i < HH; ++i) acc = fmaf(sPart[i], Wfc[i * CC + t], acc);
        out[b * CC + t] = 1.f / (1.f + expf(-acc));
    }
}

extern "C" void kernel_launch(void* const* d_in, const int* in_sizes, int n_in,
                              void* d_out, int out_size, void* d_ws, size_t ws_size,
                              hipStream_t stream) {
    const float* atoms = (const float*)d_in[0];
    const float* bonds = (const float*)d_in[1];
    const int*   edges = (const int*)d_in[2];
    const float* W1  = (const float*)d_in[3];
    const float* b1  = (const float*)d_in[4];
    const float* W2  = (const float*)d_in[5];
    const float* b2  = (const float*)d_in[6];
    const float* Wo  = (const float*)d_in[7];
    const float* bo  = (const float*)d_in[8];
    const float* Wfc = (const float*)d_in[9];
    const float* bfc = (const float*)d_in[10];
    float* out = (float*)d_out;

    ngfp_kernel<<<NB, T, 0, stream>>>(atoms, bonds, edges, W1, b1, W2, b2,
                                      Wo, bo, Wfc, bfc, out);
}